// Round 9
// baseline (105.098 us; speedup 1.0000x reference)
//
#include <hip/hip_runtime.h>

#define B_ 16
#define C_ 256
#define P_ 2048
#define BK 32
#define KT 8        // C_/BK
#define NT 136      // tiles per batch (120 strict-upper + 16 diag)
#define NT_OFF 120

typedef __attribute__((ext_vector_type(8))) short short8;
typedef __attribute__((ext_vector_type(4))) float floatx4;

// round-to-nearest-even fp32 -> bf16
__device__ inline short f2bf(float v) {
  union { float f; unsigned u; } c; c.f = v;
  unsigned r = c.u + 0x7fffu + ((c.u >> 16) & 1u);
  return (short)(r >> 16);
}

#define GLOAD_LDS16(g, l)                                          \
  __builtin_amdgcn_global_load_lds(                                \
      (const __attribute__((address_space(1))) void*)(g),          \
      (__attribute__((address_space(3))) void*)(l), 16, 0, 0)

// ---------------- kernel 1: transpose + fp32->bf16 + partial norms ----------------
// grid (P/128, B, 2): z splits the c-range in halves (4 chunks of 32 c each).
// float4 reads for 4x MLP vs r8. Partial norm^2 per z-half -> summed in GEMM.
__global__ __launch_bounds__(256, 4) void k_transpose(const float* __restrict__ x,
                                                      short* __restrict__ Xt,
                                                      float* __restrict__ nrm2p) {
  __shared__ float t[32][133];       // [c_local][p_local], pad->~conflict-free col reads
  __shared__ float red[8][32][4];
  const int p0 = blockIdx.x * 128, b = blockIdx.y, zc = blockIdx.z;
  const float* xb = x + (size_t)b * C_ * P_;
  short* xtb = Xt + (size_t)b * P_ * C_;
  const int tid = threadIdx.x;
  const int tx = tid & 31;   // 4-float col group
  const int cg = tid >> 5;   // c slot 0..7
  floatx4 s4 = (floatx4){0.f, 0.f, 0.f, 0.f};
  const int cbase = zc * 128;
#pragma unroll 1
  for (int chunk = 0; chunk < 4; ++chunk) {
    const int c0 = cbase + chunk * 32;
    float4 v[4];
#pragma unroll
    for (int i = 0; i < 4; ++i)
      v[i] = *reinterpret_cast<const float4*>(&xb[(size_t)(c0 + cg + i * 8) * P_ + p0 + tx * 4]);
#pragma unroll
    for (int i = 0; i < 4; ++i) {
      *reinterpret_cast<float4*>(&t[cg + i * 8][tx * 4]) = v[i];
      s4[0] += v[i].x * v[i].x;
      s4[1] += v[i].y * v[i].y;
      s4[2] += v[i].z * v[i].z;
      s4[3] += v[i].w * v[i].w;
    }
    __syncthreads();
    // write phase: 1024 short4 units; 8 consecutive tids -> 64B contiguous
#pragma unroll
    for (int u = 0; u < 4; ++u) {
      const int unit = tid + 256 * u;
      const int r = unit >> 3, ch = unit & 7;
      short4 w;
      w.x = f2bf(t[ch * 4 + 0][r]);
      w.y = f2bf(t[ch * 4 + 1][r]);
      w.z = f2bf(t[ch * 4 + 2][r]);
      w.w = f2bf(t[ch * 4 + 3][r]);
      *reinterpret_cast<short4*>(&xtb[(size_t)(p0 + r) * C_ + c0 + ch * 4]) = w;
    }
    __syncthreads();  // protect t before next chunk overwrites
  }
  *reinterpret_cast<floatx4*>(&red[cg][tx][0]) = s4;
  __syncthreads();
  if (tid < 128) {
    const int cgp = tid >> 2, j = tid & 3;  // p_local == tid
    float ns = 0.f;
#pragma unroll
    for (int g = 0; g < 8; ++g) ns += red[g][cgp][j];
    nrm2p[(size_t)zc * B_ * P_ + b * P_ + p0 + tid] = ns;
  }
}

// ---------------- kernel 2: symmetric Gram GEMM, XCD-chunked, 2-deep prefetch ----------------
__global__ __launch_bounds__(256, 3) void k_gemm(const short* __restrict__ Xt,
                                                 const float* __restrict__ nrm2p,
                                                 float* __restrict__ out) {
  // XCD-chunked mapping: xcd = bid%8 owns 2 full batches -> staging L2-resident
  const int bid = blockIdx.x;
  const int xcd = bid & 7;
  const int s = bid >> 3;              // 0..271
  const int b = xcd * 2 + (s >= NT);   // 2 batches per XCD
  int t = s - (s >= NT ? NT : 0);      // 0..135

  int tm, tn;
  if (t < NT_OFF) {  // strict-upper tiles (2 writes) first
    int rem = t, len = 15;
    tm = 0;
    while (rem >= len) { rem -= len; --len; ++tm; }
    tn = tm + 1 + rem;
  } else {
    tm = tn = t - NT_OFF;
  }
  const int p0 = tm * 128, q0 = tn * 128;
  const short* Xb = Xt + (size_t)b * P_ * C_;

  // 3 buffers x (A 8KB | B 8KB) = 48KB; epilogue reuses the front for etile
  __shared__ __align__(16) char smem[49152];

  const int tid = threadIdx.x;
  const int lane = tid & 63;
  const int wid = tid >> 6;
  const int wrow = wid >> 1;  // p band (64)
  const int wcol = wid & 1;   // q band (64)

  floatx4 acc[4][4];
#pragma unroll
  for (int i = 0; i < 4; ++i)
#pragma unroll
    for (int j = 0; j < 4; ++j) acc[i][j] = (floatx4){0.f, 0.f, 0.f, 0.f};

  const int K2 = C_ * 2;  // row stride bytes

  auto STAGE = [&](int buf, int kt) {
    const int kb = kt * (BK * 2);
#pragma unroll
    for (int j = 0; j < 2; ++j) {
      const int chunk = j * 4 + wid;           // 0..7, wave-uniform
      const int f = chunk * 1024 + lane * 16;
      const int row = f >> 6;
      const int inrow = f & 63;
      GLOAD_LDS16((const char*)Xb + (size_t)(p0 + row) * K2 + kb + inrow,
                  smem + buf * 16384 + chunk * 1024);
      GLOAD_LDS16((const char*)Xb + (size_t)(q0 + row) * K2 + kb + inrow,
                  smem + buf * 16384 + 8192 + chunk * 1024);
    }
  };

  STAGE(0, 0);
  STAGE(1, 1);  // 2-deep: each staged tile gets ~2 K-steps to land

  // Completion discipline (r3-r5 lesson): ds_read ISSUE before a barrier is not
  // COMPLETION -> lgkmcnt(0) before the restage barrier. Counted vmcnt never
  // drains mid-loop (T4): oldest 4 outstanding = this step's tile.
  for (int kt = 0; kt < KT; ++kt) {
    if (kt < KT - 1) {
      asm volatile("s_waitcnt vmcnt(4)\n\ts_barrier" ::: "memory");
    } else {
      asm volatile("s_waitcnt vmcnt(0)\n\ts_barrier" ::: "memory");
    }
    if (kt + 2 < KT) STAGE((kt + 2) % 3, kt + 2);  // overwrites buf freed at kt-1

    const int cur = kt % 3;
    const short* As = (const short*)(smem + cur * 16384);
    const short* Bs = (const short*)(smem + cur * 16384 + 8192);
    short8 af[4], bf[4];
#pragma unroll
    for (int mi = 0; mi < 4; ++mi) {
      const int r = wrow * 64 + mi * 16 + (lane & 15);
      af[mi] = *reinterpret_cast<const short8*>(&As[r * BK + (lane >> 4) * 8]);
    }
#pragma unroll
    for (int ni = 0; ni < 4; ++ni) {
      const int r = wcol * 64 + ni * 16 + (lane & 15);
      bf[ni] = *reinterpret_cast<const short8*>(&Bs[r * BK + (lane >> 4) * 8]);
    }
    // D[row=p][col=q]; C/D layout: col=lane&15, row=(lane>>4)*4+reg (verified r1)
#pragma unroll
    for (int mi = 0; mi < 4; ++mi)
#pragma unroll
      for (int ni = 0; ni < 4; ++ni)
        acc[mi][ni] = __builtin_amdgcn_mfma_f32_16x16x32_bf16(af[mi], bf[ni], acc[mi][ni], 0, 0, 0);

    asm volatile("s_waitcnt lgkmcnt(0)\n\ts_barrier" ::: "memory");
  }

  // ---- epilogue (non-temporal stores: output is write-once -> don't pollute L2,
  //       keeps the Xt staging slices resident) ----
  const float* n2a = nrm2p + (size_t)b * P_;
  const float* n2b = nrm2p + (size_t)B_ * P_ + (size_t)b * P_;
  float* ob = out + (size_t)b * P_ * P_;
  const int cl = lane & 15, rg4 = (lane >> 4) * 4;

  float rnq[4];
#pragma unroll
  for (int ni = 0; ni < 4; ++ni) {
    const int qc = q0 + wcol * 64 + ni * 16 + cl;
    rnq[ni] = __builtin_amdgcn_rcpf(fmaxf(sqrtf(n2a[qc] + n2b[qc]), 1e-4f));
  }
  floatx4 rnp[4];
#pragma unroll
  for (int mi = 0; mi < 4; ++mi) {
    const int pb = p0 + wrow * 64 + mi * 16 + rg4;
    const float4 pa = *reinterpret_cast<const float4*>(&n2a[pb]);
    const float4 pbv = *reinterpret_cast<const float4*>(&n2b[pb]);
    rnp[mi][0] = __builtin_amdgcn_rcpf(fmaxf(sqrtf(pa.x + pbv.x), 1e-4f));
    rnp[mi][1] = __builtin_amdgcn_rcpf(fmaxf(sqrtf(pa.y + pbv.y), 1e-4f));
    rnp[mi][2] = __builtin_amdgcn_rcpf(fmaxf(sqrtf(pa.z + pbv.z), 1e-4f));
    rnp[mi][3] = __builtin_amdgcn_rcpf(fmaxf(sqrtf(pa.w + pbv.w), 1e-4f));
  }

  // per-wave transposed bounce region reusing staging LDS (safe: final fenced
  // barrier guarantees all staging ds_reads completed; "memory" clobber pins
  // these writes below it). [64 q][20 p] fp32 per wave.
  float* etile = (float*)smem + wid * 1280;  // 4 x 5120B = 20KB < 48KB

#pragma unroll
  for (int mi = 0; mi < 4; ++mi) {
    const int prow = p0 + wrow * 64 + mi * 16 + rg4;
#pragma unroll
    for (int ni = 0; ni < 4; ++ni) {
      floatx4 vv = acc[mi][ni] * rnp[mi] * rnq[ni];
      const int qc = q0 + wcol * 64 + ni * 16 + cl;
      if (tm == tn) {
        const int d = qc - prow;  // diag when prow + r == qc
        if (d >= 0 && d < 4) vv[d] = 1.0f;
      }
      // normal tile: 4 scalar nt stores -> 4 x 64B segments per instruction
      __builtin_nontemporal_store(vv[0], &ob[(size_t)(prow + 0) * P_ + qc]);
      __builtin_nontemporal_store(vv[1], &ob[(size_t)(prow + 1) * P_ + qc]);
      __builtin_nontemporal_store(vv[2], &ob[(size_t)(prow + 2) * P_ + qc]);
      __builtin_nontemporal_store(vv[3], &ob[(size_t)(prow + 3) * P_ + qc]);
      if (tm != tn)  // stash transposed: lane's 4 consecutive p at row q
        *reinterpret_cast<floatx4*>(&etile[(ni * 16 + cl) * 20 + rg4]) = vv;
    }
    if (tm != tn) {
      // coalesced mirror store for this 16-col (p) slab: rows q, 64B segments
      const int pcb = p0 + wrow * 64 + mi * 16;
#pragma unroll
      for (int i = 0; i < 4; ++i) {
        const int qq = i * 16 + (lane >> 2);
        const floatx4 mv = *reinterpret_cast<const floatx4*>(&etile[qq * 20 + (lane & 3) * 4]);
        __builtin_nontemporal_store(
            mv, reinterpret_cast<floatx4*>(
                    &ob[(size_t)(q0 + wcol * 64 + qq) * P_ + pcb + (lane & 3) * 4]));
      }
    }
  }
}

extern "C" void kernel_launch(void* const* d_in, const int* in_sizes, int n_in,
                              void* d_out, int out_size, void* d_ws, size_t ws_size,
                              hipStream_t stream) {
  const float* x = (const float*)d_in[0];
  float* out = (float*)d_out;

  short* Xt = (short*)d_ws;                                                     // 16 MB
  float* nrm2p = (float*)((char*)d_ws + (size_t)B_ * P_ * C_ * sizeof(short));  // 2x128 KB

  k_transpose<<<dim3(P_ / 128, B_, 2), 256, 0, stream>>>(x, Xt, nrm2p);
  k_gemm<<<dim3(NT * B_), 256, 0, stream>>>(Xt, nrm2p, out);
}

// Round 10
// 86.042 us; speedup vs baseline: 1.2215x; 1.2215x over previous
//
#include <hip/hip_runtime.h>

#define B_ 16
#define C_ 256
#define P_ 2048
#define BK 32
#define KT 8        // C_/BK
#define NT 136      // tiles per batch (120 strict-upper + 16 diag)
#define NT_OFF 120

typedef __attribute__((ext_vector_type(8))) short short8;
typedef __attribute__((ext_vector_type(4))) float floatx4;

// round-to-nearest-even fp32 -> bf16
__device__ inline short f2bf(float v) {
  union { float f; unsigned u; } c; c.f = v;
  unsigned r = c.u + 0x7fffu + ((c.u >> 16) & 1u);
  return (short)(r >> 16);
}

#define GLOAD_LDS16(g, l)                                          \
  __builtin_amdgcn_global_load_lds(                                \
      (const __attribute__((address_space(1))) void*)(g),          \
      (__attribute__((address_space(3))) void*)(l), 16, 0, 0)

// ---------------- kernel 1: transpose + fp32->bf16 + partial norms ----------------
// grid (P/128, B, 2): z splits the c-range in halves (4 chunks of 32 c each).
// float4 reads. Partial norm^2 per z-half -> summed in GEMM epilogue.
__global__ __launch_bounds__(256, 4) void k_transpose(const float* __restrict__ x,
                                                      short* __restrict__ Xt,
                                                      float* __restrict__ nrm2p) {
  __shared__ float t[32][133];       // [c_local][p_local], padded
  __shared__ float red[8][32][4];
  const int p0 = blockIdx.x * 128, b = blockIdx.y, zc = blockIdx.z;
  const float* xb = x + (size_t)b * C_ * P_;
  short* xtb = Xt + (size_t)b * P_ * C_;
  const int tid = threadIdx.x;
  const int tx = tid & 31;   // 4-float col group
  const int cg = tid >> 5;   // c slot 0..7
  floatx4 s4 = (floatx4){0.f, 0.f, 0.f, 0.f};
  const int cbase = zc * 128;
#pragma unroll 1
  for (int chunk = 0; chunk < 4; ++chunk) {
    const int c0 = cbase + chunk * 32;
    float4 v[4];
#pragma unroll
    for (int i = 0; i < 4; ++i)
      v[i] = *reinterpret_cast<const float4*>(&xb[(size_t)(c0 + cg + i * 8) * P_ + p0 + tx * 4]);
#pragma unroll
    for (int i = 0; i < 4; ++i) {
      *reinterpret_cast<float4*>(&t[cg + i * 8][tx * 4]) = v[i];
      s4[0] += v[i].x * v[i].x;
      s4[1] += v[i].y * v[i].y;
      s4[2] += v[i].z * v[i].z;
      s4[3] += v[i].w * v[i].w;
    }
    __syncthreads();
    // write phase: 1024 short4 units; 8 consecutive tids -> 64B contiguous
#pragma unroll
    for (int u = 0; u < 4; ++u) {
      const int unit = tid + 256 * u;
      const int r = unit >> 3, ch = unit & 7;
      short4 w;
      w.x = f2bf(t[ch * 4 + 0][r]);
      w.y = f2bf(t[ch * 4 + 1][r]);
      w.z = f2bf(t[ch * 4 + 2][r]);
      w.w = f2bf(t[ch * 4 + 3][r]);
      *reinterpret_cast<short4*>(&xtb[(size_t)(p0 + r) * C_ + c0 + ch * 4]) = w;
    }
    __syncthreads();  // protect t before next chunk overwrites
  }
  *reinterpret_cast<floatx4*>(&red[cg][tx][0]) = s4;
  __syncthreads();
  if (tid < 128) {
    const int cgp = tid >> 2, j = tid & 3;  // p_local == tid
    float ns = 0.f;
#pragma unroll
    for (int g = 0; g < 8; ++g) ns += red[g][cgp][j];
    nrm2p[(size_t)zc * B_ * P_ + b * P_ + p0 + tid] = ns;
  }
}

// ---------------- kernel 2: symmetric Gram GEMM, XCD-chunked, 2-deep prefetch ----------------
__global__ __launch_bounds__(256, 3) void k_gemm(const short* __restrict__ Xt,
                                                 const float* __restrict__ nrm2p,
                                                 float* __restrict__ out) {
  // XCD-chunked mapping: xcd = bid%8 owns 2 full batches -> staging L2-resident
  const int bid = blockIdx.x;
  const int xcd = bid & 7;
  const int s = bid >> 3;              // 0..271
  const int b = xcd * 2 + (s >= NT);   // 2 batches per XCD
  int t = s - (s >= NT ? NT : 0);      // 0..135

  int tm, tn;
  if (t < NT_OFF) {  // strict-upper tiles (2 writes) first
    int rem = t, len = 15;
    tm = 0;
    while (rem >= len) { rem -= len; --len; ++tm; }
    tn = tm + 1 + rem;
  } else {
    tm = tn = t - NT_OFF;
  }
  const int p0 = tm * 128, q0 = tn * 128;
  const short* Xb = Xt + (size_t)b * P_ * C_;

  // 3 buffers x (A 8KB | B 8KB) = 48KB; epilogue reuses the front for etile
  __shared__ __align__(16) char smem[49152];

  const int tid = threadIdx.x;
  const int lane = tid & 63;
  const int wid = tid >> 6;
  const int wrow = wid >> 1;  // p band (64)
  const int wcol = wid & 1;   // q band (64)

  floatx4 acc[4][4];
#pragma unroll
  for (int i = 0; i < 4; ++i)
#pragma unroll
    for (int j = 0; j < 4; ++j) acc[i][j] = (floatx4){0.f, 0.f, 0.f, 0.f};

  const int K2 = C_ * 2;  // row stride bytes

  auto STAGE = [&](int buf, int kt) {
    const int kb = kt * (BK * 2);
#pragma unroll
    for (int j = 0; j < 2; ++j) {
      const int chunk = j * 4 + wid;           // 0..7, wave-uniform
      const int f = chunk * 1024 + lane * 16;
      const int row = f >> 6;
      const int inrow = f & 63;
      GLOAD_LDS16((const char*)Xb + (size_t)(p0 + row) * K2 + kb + inrow,
                  smem + buf * 16384 + chunk * 1024);
      GLOAD_LDS16((const char*)Xb + (size_t)(q0 + row) * K2 + kb + inrow,
                  smem + buf * 16384 + 8192 + chunk * 1024);
    }
  };

  STAGE(0, 0);
  STAGE(1, 1);  // 2-deep: each staged tile gets ~2 K-steps to land

  // Completion discipline (r3-r5 lesson): ds_read ISSUE before a barrier is not
  // COMPLETION -> lgkmcnt(0) before the restage barrier. Counted vmcnt never
  // drains mid-loop (T4): oldest 4 outstanding = this step's tile.
  for (int kt = 0; kt < KT; ++kt) {
    if (kt < KT - 1) {
      asm volatile("s_waitcnt vmcnt(4)\n\ts_barrier" ::: "memory");
    } else {
      asm volatile("s_waitcnt vmcnt(0)\n\ts_barrier" ::: "memory");
    }
    if (kt + 2 < KT) STAGE((kt + 2) % 3, kt + 2);  // overwrites buf freed at kt-1

    const int cur = kt % 3;
    const short* As = (const short*)(smem + cur * 16384);
    const short* Bs = (const short*)(smem + cur * 16384 + 8192);
    short8 af[4], bf[4];
#pragma unroll
    for (int mi = 0; mi < 4; ++mi) {
      const int r = wrow * 64 + mi * 16 + (lane & 15);
      af[mi] = *reinterpret_cast<const short8*>(&As[r * BK + (lane >> 4) * 8]);
    }
#pragma unroll
    for (int ni = 0; ni < 4; ++ni) {
      const int r = wcol * 64 + ni * 16 + (lane & 15);
      bf[ni] = *reinterpret_cast<const short8*>(&Bs[r * BK + (lane >> 4) * 8]);
    }
    // D[row=p][col=q]; C/D layout: col=lane&15, row=(lane>>4)*4+reg (verified r1)
#pragma unroll
    for (int mi = 0; mi < 4; ++mi)
#pragma unroll
      for (int ni = 0; ni < 4; ++ni)
        acc[mi][ni] = __builtin_amdgcn_mfma_f32_16x16x32_bf16(af[mi], bf[ni], acc[mi][ni], 0, 0, 0);

    asm volatile("s_waitcnt lgkmcnt(0)\n\ts_barrier" ::: "memory");
  }

  // ---- epilogue (plain stores; r9's nt-stores regressed: bypassing L2 turned
  //      our 64B half-line segments into HBM partial-line writes) ----
  const float* n2a = nrm2p + (size_t)b * P_;
  const float* n2b = nrm2p + (size_t)B_ * P_ + (size_t)b * P_;
  float* ob = out + (size_t)b * P_ * P_;
  const int cl = lane & 15, rg4 = (lane >> 4) * 4;

  float rnq[4];
#pragma unroll
  for (int ni = 0; ni < 4; ++ni) {
    const int qc = q0 + wcol * 64 + ni * 16 + cl;
    rnq[ni] = __builtin_amdgcn_rcpf(fmaxf(sqrtf(n2a[qc] + n2b[qc]), 1e-4f));
  }
  floatx4 rnp[4];
#pragma unroll
  for (int mi = 0; mi < 4; ++mi) {
    const int pb = p0 + wrow * 64 + mi * 16 + rg4;
    const float4 pa = *reinterpret_cast<const float4*>(&n2a[pb]);
    const float4 pbv = *reinterpret_cast<const float4*>(&n2b[pb]);
    rnp[mi][0] = __builtin_amdgcn_rcpf(fmaxf(sqrtf(pa.x + pbv.x), 1e-4f));
    rnp[mi][1] = __builtin_amdgcn_rcpf(fmaxf(sqrtf(pa.y + pbv.y), 1e-4f));
    rnp[mi][2] = __builtin_amdgcn_rcpf(fmaxf(sqrtf(pa.z + pbv.z), 1e-4f));
    rnp[mi][3] = __builtin_amdgcn_rcpf(fmaxf(sqrtf(pa.w + pbv.w), 1e-4f));
  }

  // per-wave transposed bounce region reusing staging LDS (safe: final fenced
  // barrier guarantees all staging ds_reads completed; "memory" clobber pins
  // these writes below it). [64 q][20 p] fp32 per wave.
  float* etile = (float*)smem + wid * 1280;  // 4 x 5120B = 20KB < 48KB

#pragma unroll
  for (int mi = 0; mi < 4; ++mi) {
    const int prow = p0 + wrow * 64 + mi * 16 + rg4;
#pragma unroll
    for (int ni = 0; ni < 4; ++ni) {
      floatx4 vv = acc[mi][ni] * rnp[mi] * rnq[ni];
      const int qc = q0 + wcol * 64 + ni * 16 + cl;
      if (tm == tn) {
        const int d = qc - prow;  // diag when prow + r == qc
        if (d >= 0 && d < 4) vv[d] = 1.0f;
      }
      // normal tile: 4 scalar stores -> 4 x 64B segments per instruction
      ob[(size_t)(prow + 0) * P_ + qc] = vv[0];
      ob[(size_t)(prow + 1) * P_ + qc] = vv[1];
      ob[(size_t)(prow + 2) * P_ + qc] = vv[2];
      ob[(size_t)(prow + 3) * P_ + qc] = vv[3];
      if (tm != tn)  // stash transposed: lane's 4 consecutive p at row q
        *reinterpret_cast<floatx4*>(&etile[(ni * 16 + cl) * 20 + rg4]) = vv;
    }
    if (tm != tn) {
      // coalesced mirror store for this 16-col (p) slab: rows q, 64B segments
      const int pcb = p0 + wrow * 64 + mi * 16;
#pragma unroll
      for (int i = 0; i < 4; ++i) {
        const int qq = i * 16 + (lane >> 2);
        const floatx4 mv = *reinterpret_cast<const floatx4*>(&etile[qq * 20 + (lane & 3) * 4]);
        *reinterpret_cast<floatx4*>(
            &ob[(size_t)(q0 + wcol * 64 + qq) * P_ + pcb + (lane & 3) * 4]) = mv;
      }
    }
  }
}

extern "C" void kernel_launch(void* const* d_in, const int* in_sizes, int n_in,
                              void* d_out, int out_size, void* d_ws, size_t ws_size,
                              hipStream_t stream) {
  const float* x = (const float*)d_in[0];
  float* out = (float*)d_out;

  short* Xt = (short*)d_ws;                                                     // 16 MB
  float* nrm2p = (float*)((char*)d_ws + (size_t)B_ * P_ * C_ * sizeof(short));  // 2x128 KB

  k_transpose<<<dim3(P_ / 128, B_, 2), 256, 0, stream>>>(x, Xt, nrm2p);
  k_gemm<<<dim3(NT * B_), 256, 0, stream>>>(Xt, nrm2p, out);
}

// Round 11
// 83.301 us; speedup vs baseline: 1.2617x; 1.0329x over previous
//
#include <hip/hip_runtime.h>

#define B_ 16
#define C_ 256
#define P_ 2048
#define BK 32
#define KT 8        // C_/BK
#define NT 136      // tiles per batch (120 strict-upper + 16 diag)
#define NT_OFF 120

typedef __attribute__((ext_vector_type(8))) short short8;
typedef __attribute__((ext_vector_type(4))) float floatx4;

// round-to-nearest-even fp32 -> bf16
__device__ inline short f2bf(float v) {
  union { float f; unsigned u; } c; c.f = v;
  unsigned r = c.u + 0x7fffu + ((c.u >> 16) & 1u);
  return (short)(r >> 16);
}

#define GLOAD_LDS16(g, l)                                          \
  __builtin_amdgcn_global_load_lds(                                \
      (const __attribute__((address_space(1))) void*)(g),          \
      (__attribute__((address_space(3))) void*)(l), 16, 0, 0)

// ---------------- kernel 1: transpose + fp32->bf16 + partial norms ----------------
// grid (P/128, B, 2): z halves the c-range (4 chunks of 32 c each).
// float4 reads (16B/lane); double-buffered LDS tile -> 1 barrier per chunk.
__global__ __launch_bounds__(256, 4) void k_transpose(const float* __restrict__ x,
                                                      short* __restrict__ Xt,
                                                      float* __restrict__ nrm2p) {
  __shared__ float t[2][32][133];    // dbuf: chunk k uses t[k&1]; WAR is 2 chunks away
  __shared__ float red[8][32][4];
  const int p0 = blockIdx.x * 128, b = blockIdx.y, zc = blockIdx.z;
  const float* xb = x + (size_t)b * C_ * P_;
  short* xtb = Xt + (size_t)b * P_ * C_;
  const int tid = threadIdx.x;
  const int tx = tid & 31;   // 4-float col group
  const int cg = tid >> 5;   // c slot 0..7
  floatx4 s4 = (floatx4){0.f, 0.f, 0.f, 0.f};
  const int cbase = zc * 128;
#pragma unroll 1
  for (int chunk = 0; chunk < 4; ++chunk) {
    const int c0 = cbase + chunk * 32;
    const int tb = chunk & 1;
    float4 v[4];
#pragma unroll
    for (int i = 0; i < 4; ++i)
      v[i] = *reinterpret_cast<const float4*>(&xb[(size_t)(c0 + cg + i * 8) * P_ + p0 + tx * 4]);
#pragma unroll
    for (int i = 0; i < 4; ++i) {
      *reinterpret_cast<float4*>(&t[tb][cg + i * 8][tx * 4]) = v[i];
      s4[0] += v[i].x * v[i].x;
      s4[1] += v[i].y * v[i].y;
      s4[2] += v[i].z * v[i].z;
      s4[3] += v[i].w * v[i].w;
    }
    __syncthreads();  // this chunk's tile visible to all
    // write phase: 1024 short4 units; 8 consecutive tids -> 64B contiguous
#pragma unroll
    for (int u = 0; u < 4; ++u) {
      const int unit = tid + 256 * u;
      const int r = unit >> 3, ch = unit & 7;
      short4 w;
      w.x = f2bf(t[tb][ch * 4 + 0][r]);
      w.y = f2bf(t[tb][ch * 4 + 1][r]);
      w.z = f2bf(t[tb][ch * 4 + 2][r]);
      w.w = f2bf(t[tb][ch * 4 + 3][r]);
      *reinterpret_cast<short4*>(&xtb[(size_t)(p0 + r) * C_ + c0 + ch * 4]) = w;
    }
    // no second barrier: next chunk writes t[tb^1]; t[tb] reused 2 chunks later,
    // separated by that chunk's own __syncthreads
  }
  *reinterpret_cast<floatx4*>(&red[cg][tx][0]) = s4;
  __syncthreads();
  if (tid < 128) {
    const int cgp = tid >> 2, j = tid & 3;  // p_local == tid
    float ns = 0.f;
#pragma unroll
    for (int g = 0; g < 8; ++g) ns += red[g][cgp][j];
    nrm2p[(size_t)zc * B_ * P_ + b * P_ + p0 + tid] = ns;
  }
}

// ---------------- kernel 2: symmetric Gram GEMM, XCD-chunked (r8's proven loop) ----------------
__global__ __launch_bounds__(256, 3) void k_gemm(const short* __restrict__ Xt,
                                                 const float* __restrict__ nrm2p,
                                                 float* __restrict__ out) {
  // XCD-chunked mapping: xcd = bid%8 owns 2 full batches -> staging L2-resident
  const int bid = blockIdx.x;
  const int xcd = bid & 7;
  const int s = bid >> 3;              // 0..271
  const int b = xcd * 2 + (s >= NT);   // 2 batches per XCD
  int t = s - (s >= NT ? NT : 0);      // 0..135

  int tm, tn;
  if (t < NT_OFF) {  // strict-upper tiles (2 writes) first
    int rem = t, len = 15;
    tm = 0;
    while (rem >= len) { rem -= len; --len; ++tm; }
    tn = tm + 1 + rem;
  } else {
    tm = tn = t - NT_OFF;
  }
  const int p0 = tm * 128, q0 = tn * 128;
  const short* Xb = Xt + (size_t)b * P_ * C_;

  __shared__ __align__(16) char smem[32768];  // As[2][8K] | Bs[2][8K]; epilogue reuse

  const int tid = threadIdx.x;
  const int lane = tid & 63;
  const int wid = tid >> 6;
  const int wrow = wid >> 1;  // p band (64)
  const int wcol = wid & 1;   // q band (64)

  floatx4 acc[4][4];
#pragma unroll
  for (int i = 0; i < 4; ++i)
#pragma unroll
    for (int j = 0; j < 4; ++j) acc[i][j] = (floatx4){0.f, 0.f, 0.f, 0.f};

  const int K2 = C_ * 2;  // row stride bytes

  auto STAGE = [&](int buf, int kt) {
    const int kb = kt * (BK * 2);
#pragma unroll
    for (int j = 0; j < 2; ++j) {
      const int chunk = j * 4 + wid;           // 0..7, wave-uniform
      const int f = chunk * 1024 + lane * 16;
      const int row = f >> 6;
      const int inrow = f & 63;
      GLOAD_LDS16((const char*)Xb + (size_t)(p0 + row) * K2 + kb + inrow,
                  smem + buf * 8192 + chunk * 1024);
      GLOAD_LDS16((const char*)Xb + (size_t)(q0 + row) * K2 + kb + inrow,
                  smem + 16384 + buf * 8192 + chunk * 1024);
    }
  };

  STAGE(0, 0);

  // r6/r8's proven loop: counted vmcnt (never drained mid-loop) + the
  // lgkmcnt(0)-before-restage-barrier completion discipline (r3-r5 root cause:
  // ds_read ISSUE before a barrier is not COMPLETION).
  for (int kt = 0; kt < KT; ++kt) {
    const int cur = kt & 1;
    if (kt < KT - 1) {
      STAGE(cur ^ 1, kt + 1);
      // 8 outstanding; wait to <=4 -> my 4 cur-tile loads (oldest) landed
      asm volatile("s_waitcnt vmcnt(4)\n\ts_barrier" ::: "memory");
    } else {
      asm volatile("s_waitcnt vmcnt(0)\n\ts_barrier" ::: "memory");
    }

    const short* As = (const short*)(smem + cur * 8192);
    const short* Bs = (const short*)(smem + 16384 + cur * 8192);
    short8 af[4], bf[4];
#pragma unroll
    for (int mi = 0; mi < 4; ++mi) {
      const int r = wrow * 64 + mi * 16 + (lane & 15);
      af[mi] = *reinterpret_cast<const short8*>(&As[r * BK + (lane >> 4) * 8]);
    }
#pragma unroll
    for (int ni = 0; ni < 4; ++ni) {
      const int r = wcol * 64 + ni * 16 + (lane & 15);
      bf[ni] = *reinterpret_cast<const short8*>(&Bs[r * BK + (lane >> 4) * 8]);
    }
    // D[row=p][col=q]; C/D layout: col=lane&15, row=(lane>>4)*4+reg (verified r1)
#pragma unroll
    for (int mi = 0; mi < 4; ++mi)
#pragma unroll
      for (int ni = 0; ni < 4; ++ni)
        acc[mi][ni] = __builtin_amdgcn_mfma_f32_16x16x32_bf16(af[mi], bf[ni], acc[mi][ni], 0, 0, 0);

    asm volatile("s_waitcnt lgkmcnt(0)\n\ts_barrier" ::: "memory");
  }

  // ---- epilogue (plain stores; nt-stores proven regressive in r9) ----
  const float* n2a = nrm2p + (size_t)b * P_;
  const float* n2b = nrm2p + (size_t)B_ * P_ + (size_t)b * P_;
  float* ob = out + (size_t)b * P_ * P_;
  const int cl = lane & 15, rg4 = (lane >> 4) * 4;

  float rnq[4];
#pragma unroll
  for (int ni = 0; ni < 4; ++ni) {
    const int qc = q0 + wcol * 64 + ni * 16 + cl;
    rnq[ni] = __builtin_amdgcn_rcpf(fmaxf(sqrtf(n2a[qc] + n2b[qc]), 1e-4f));
  }
  floatx4 rnp[4];
#pragma unroll
  for (int mi = 0; mi < 4; ++mi) {
    const int pb = p0 + wrow * 64 + mi * 16 + rg4;
    const float4 pa = *reinterpret_cast<const float4*>(&n2a[pb]);
    const float4 pbv = *reinterpret_cast<const float4*>(&n2b[pb]);
    rnp[mi][0] = __builtin_amdgcn_rcpf(fmaxf(sqrtf(pa.x + pbv.x), 1e-4f));
    rnp[mi][1] = __builtin_amdgcn_rcpf(fmaxf(sqrtf(pa.y + pbv.y), 1e-4f));
    rnp[mi][2] = __builtin_amdgcn_rcpf(fmaxf(sqrtf(pa.z + pbv.z), 1e-4f));
    rnp[mi][3] = __builtin_amdgcn_rcpf(fmaxf(sqrtf(pa.w + pbv.w), 1e-4f));
  }

  // per-wave transposed bounce region reusing staging LDS (safe: final fenced
  // barrier guarantees all staging ds_reads completed; "memory" clobber pins
  // these writes below it). [64 q][20 p] fp32 per wave.
  float* etile = (float*)smem + wid * 1280;  // 4 x 5120B = 20KB < 32KB

#pragma unroll
  for (int mi = 0; mi < 4; ++mi) {
    const int prow = p0 + wrow * 64 + mi * 16 + rg4;
#pragma unroll
    for (int ni = 0; ni < 4; ++ni) {
      floatx4 vv = acc[mi][ni] * rnp[mi] * rnq[ni];
      const int qc = q0 + wcol * 64 + ni * 16 + cl;
      if (tm == tn) {
        const int d = qc - prow;  // diag when prow + r == qc
        if (d >= 0 && d < 4) vv[d] = 1.0f;
      }
      // normal tile: 4 scalar stores -> 4 x 64B segments per instruction
      ob[(size_t)(prow + 0) * P_ + qc] = vv[0];
      ob[(size_t)(prow + 1) * P_ + qc] = vv[1];
      ob[(size_t)(prow + 2) * P_ + qc] = vv[2];
      ob[(size_t)(prow + 3) * P_ + qc] = vv[3];
      if (tm != tn)  // stash transposed: lane's 4 consecutive p at row q
        *reinterpret_cast<floatx4*>(&etile[(ni * 16 + cl) * 20 + rg4]) = vv;
    }
    if (tm != tn) {
      // coalesced mirror store for this 16-col (p) slab: rows q, 64B segments
      const int pcb = p0 + wrow * 64 + mi * 16;
#pragma unroll
      for (int i = 0; i < 4; ++i) {
        const int qq = i * 16 + (lane >> 2);
        const floatx4 mv = *reinterpret_cast<const floatx4*>(&etile[qq * 20 + (lane & 3) * 4]);
        *reinterpret_cast<floatx4*>(
            &ob[(size_t)(q0 + wcol * 64 + qq) * P_ + pcb + (lane & 3) * 4]) = mv;
      }
    }
  }
}

extern "C" void kernel_launch(void* const* d_in, const int* in_sizes, int n_in,
                              void* d_out, int out_size, void* d_ws, size_t ws_size,
                              hipStream_t stream) {
  const float* x = (const float*)d_in[0];
  float* out = (float*)d_out;

  short* Xt = (short*)d_ws;                                                     // 16 MB
  float* nrm2p = (float*)((char*)d_ws + (size_t)B_ * P_ * C_ * sizeof(short));  // 2x128 KB

  k_transpose<<<dim3(P_ / 128, B_, 2), 256, 0, stream>>>(x, Xt, nrm2p);
  k_gemm<<<dim3(NT * B_), 256, 0, stream>>>(Xt, nrm2p, out);
}

// Round 12
// 81.776 us; speedup vs baseline: 1.2852x; 1.0187x over previous
//
#include <hip/hip_runtime.h>

#define B_ 16
#define C_ 256
#define P_ 2048
#define BK 32
#define KT 8        // C_/BK
#define NT 136      // tiles per batch (120 strict-upper + 16 diag)
#define NT_OFF 120

typedef __attribute__((ext_vector_type(8))) short short8;
typedef __attribute__((ext_vector_type(4))) float floatx4;

// round-to-nearest-even fp32 -> bf16
__device__ inline short f2bf(float v) {
  union { float f; unsigned u; } c; c.f = v;
  unsigned r = c.u + 0x7fffu + ((c.u >> 16) & 1u);
  return (short)(r >> 16);
}

#define GLOAD_LDS16(g, l)                                          \
  __builtin_amdgcn_global_load_lds(                                \
      (const __attribute__((address_space(1))) void*)(g),          \
      (__attribute__((address_space(3))) void*)(l), 16, 0, 0)

// ---------------- kernel 1: transpose + fp32->bf16 + partial norms ----------------
// grid (P/128, B, 2): z halves the c-range (4 chunks of 32 c each).
// float4 reads (16B/lane); double-buffered LDS tile -> 1 barrier per chunk.
__global__ __launch_bounds__(256, 4) void k_transpose(const float* __restrict__ x,
                                                      short* __restrict__ Xt,
                                                      float* __restrict__ nrm2p) {
  __shared__ float t[2][32][133];    // dbuf: chunk k uses t[k&1]; WAR is 2 chunks away
  __shared__ float red[8][32][4];
  const int p0 = blockIdx.x * 128, b = blockIdx.y, zc = blockIdx.z;
  const float* xb = x + (size_t)b * C_ * P_;
  short* xtb = Xt + (size_t)b * P_ * C_;
  const int tid = threadIdx.x;
  const int tx = tid & 31;   // 4-float col group
  const int cg = tid >> 5;   // c slot 0..7
  floatx4 s4 = (floatx4){0.f, 0.f, 0.f, 0.f};
  const int cbase = zc * 128;
#pragma unroll 1
  for (int chunk = 0; chunk < 4; ++chunk) {
    const int c0 = cbase + chunk * 32;
    const int tb = chunk & 1;
    float4 v[4];
#pragma unroll
    for (int i = 0; i < 4; ++i)
      v[i] = *reinterpret_cast<const float4*>(&xb[(size_t)(c0 + cg + i * 8) * P_ + p0 + tx * 4]);
#pragma unroll
    for (int i = 0; i < 4; ++i) {
      *reinterpret_cast<float4*>(&t[tb][cg + i * 8][tx * 4]) = v[i];
      s4[0] += v[i].x * v[i].x;
      s4[1] += v[i].y * v[i].y;
      s4[2] += v[i].z * v[i].z;
      s4[3] += v[i].w * v[i].w;
    }
    __syncthreads();  // this chunk's tile visible to all
    // write phase: 1024 short4 units; 8 consecutive tids -> 64B contiguous
#pragma unroll
    for (int u = 0; u < 4; ++u) {
      const int unit = tid + 256 * u;
      const int r = unit >> 3, ch = unit & 7;
      short4 w;
      w.x = f2bf(t[tb][ch * 4 + 0][r]);
      w.y = f2bf(t[tb][ch * 4 + 1][r]);
      w.z = f2bf(t[tb][ch * 4 + 2][r]);
      w.w = f2bf(t[tb][ch * 4 + 3][r]);
      *reinterpret_cast<short4*>(&xtb[(size_t)(p0 + r) * C_ + c0 + ch * 4]) = w;
    }
    // no second barrier: next chunk writes t[tb^1]; t[tb] reused 2 chunks later,
    // separated by that chunk's own __syncthreads
  }
  *reinterpret_cast<floatx4*>(&red[cg][tx][0]) = s4;
  __syncthreads();
  if (tid < 128) {
    const int cgp = tid >> 2, j = tid & 3;  // p_local == tid
    float ns = 0.f;
#pragma unroll
    for (int g = 0; g < 8; ++g) ns += red[g][cgp][j];
    nrm2p[(size_t)zc * B_ * P_ + b * P_ + p0 + tid] = ns;
  }
}

// ---------------- kernel 2: symmetric Gram GEMM, XCD-chunked ----------------
// SINGLE LEVER vs r11: occupancy 3 -> 4 blocks/CU (16 waves) to raise
// store-stream concurrency; GEMM writes at only 3.7 TB/s vs fills' 6.5+.
__global__ __launch_bounds__(256, 4) void k_gemm(const short* __restrict__ Xt,
                                                 const float* __restrict__ nrm2p,
                                                 float* __restrict__ out) {
  // XCD-chunked mapping: xcd = bid%8 owns 2 full batches -> staging L2-resident
  const int bid = blockIdx.x;
  const int xcd = bid & 7;
  const int s = bid >> 3;              // 0..271
  const int b = xcd * 2 + (s >= NT);   // 2 batches per XCD
  int t = s - (s >= NT ? NT : 0);      // 0..135

  int tm, tn;
  if (t < NT_OFF) {  // strict-upper tiles (2 writes) first
    int rem = t, len = 15;
    tm = 0;
    while (rem >= len) { rem -= len; --len; ++tm; }
    tn = tm + 1 + rem;
  } else {
    tm = tn = t - NT_OFF;
  }
  const int p0 = tm * 128, q0 = tn * 128;
  const short* Xb = Xt + (size_t)b * P_ * C_;

  __shared__ __align__(16) char smem[32768];  // As[2][8K] | Bs[2][8K]; epilogue reuse

  const int tid = threadIdx.x;
  const int lane = tid & 63;
  const int wid = tid >> 6;
  const int wrow = wid >> 1;  // p band (64)
  const int wcol = wid & 1;   // q band (64)

  floatx4 acc[4][4];
#pragma unroll
  for (int i = 0; i < 4; ++i)
#pragma unroll
    for (int j = 0; j < 4; ++j) acc[i][j] = (floatx4){0.f, 0.f, 0.f, 0.f};

  const int K2 = C_ * 2;  // row stride bytes

  auto STAGE = [&](int buf, int kt) {
    const int kb = kt * (BK * 2);
#pragma unroll
    for (int j = 0; j < 2; ++j) {
      const int chunk = j * 4 + wid;           // 0..7, wave-uniform
      const int f = chunk * 1024 + lane * 16;
      const int row = f >> 6;
      const int inrow = f & 63;
      GLOAD_LDS16((const char*)Xb + (size_t)(p0 + row) * K2 + kb + inrow,
                  smem + buf * 8192 + chunk * 1024);
      GLOAD_LDS16((const char*)Xb + (size_t)(q0 + row) * K2 + kb + inrow,
                  smem + 16384 + buf * 8192 + chunk * 1024);
    }
  };

  STAGE(0, 0);

  // r6/r8's proven loop: counted vmcnt (never drained mid-loop) + the
  // lgkmcnt(0)-before-restage-barrier completion discipline (r3-r5 root cause:
  // ds_read ISSUE before a barrier is not COMPLETION).
  for (int kt = 0; kt < KT; ++kt) {
    const int cur = kt & 1;
    if (kt < KT - 1) {
      STAGE(cur ^ 1, kt + 1);
      // 8 outstanding; wait to <=4 -> my 4 cur-tile loads (oldest) landed
      asm volatile("s_waitcnt vmcnt(4)\n\ts_barrier" ::: "memory");
    } else {
      asm volatile("s_waitcnt vmcnt(0)\n\ts_barrier" ::: "memory");
    }

    const short* As = (const short*)(smem + cur * 8192);
    const short* Bs = (const short*)(smem + 16384 + cur * 8192);
    short8 af[4], bf[4];
#pragma unroll
    for (int mi = 0; mi < 4; ++mi) {
      const int r = wrow * 64 + mi * 16 + (lane & 15);
      af[mi] = *reinterpret_cast<const short8*>(&As[r * BK + (lane >> 4) * 8]);
    }
#pragma unroll
    for (int ni = 0; ni < 4; ++ni) {
      const int r = wcol * 64 + ni * 16 + (lane & 15);
      bf[ni] = *reinterpret_cast<const short8*>(&Bs[r * BK + (lane >> 4) * 8]);
    }
    // D[row=p][col=q]; C/D layout: col=lane&15, row=(lane>>4)*4+reg (verified r1)
#pragma unroll
    for (int mi = 0; mi < 4; ++mi)
#pragma unroll
      for (int ni = 0; ni < 4; ++ni)
        acc[mi][ni] = __builtin_amdgcn_mfma_f32_16x16x32_bf16(af[mi], bf[ni], acc[mi][ni], 0, 0, 0);

    asm volatile("s_waitcnt lgkmcnt(0)\n\ts_barrier" ::: "memory");
  }

  // ---- epilogue (plain stores; nt-stores proven regressive in r9) ----
  const float* n2a = nrm2p + (size_t)b * P_;
  const float* n2b = nrm2p + (size_t)B_ * P_ + (size_t)b * P_;
  float* ob = out + (size_t)b * P_ * P_;
  const int cl = lane & 15, rg4 = (lane >> 4) * 4;

  float rnq[4];
#pragma unroll
  for (int ni = 0; ni < 4; ++ni) {
    const int qc = q0 + wcol * 64 + ni * 16 + cl;
    rnq[ni] = __builtin_amdgcn_rcpf(fmaxf(sqrtf(n2a[qc] + n2b[qc]), 1e-4f));
  }
  floatx4 rnp[4];
#pragma unroll
  for (int mi = 0; mi < 4; ++mi) {
    const int pb = p0 + wrow * 64 + mi * 16 + rg4;
    const float4 pa = *reinterpret_cast<const float4*>(&n2a[pb]);
    const float4 pbv = *reinterpret_cast<const float4*>(&n2b[pb]);
    rnp[mi][0] = __builtin_amdgcn_rcpf(fmaxf(sqrtf(pa.x + pbv.x), 1e-4f));
    rnp[mi][1] = __builtin_amdgcn_rcpf(fmaxf(sqrtf(pa.y + pbv.y), 1e-4f));
    rnp[mi][2] = __builtin_amdgcn_rcpf(fmaxf(sqrtf(pa.z + pbv.z), 1e-4f));
    rnp[mi][3] = __builtin_amdgcn_rcpf(fmaxf(sqrtf(pa.w + pbv.w), 1e-4f));
  }

  // per-wave transposed bounce region reusing staging LDS (safe: final fenced
  // barrier guarantees all staging ds_reads completed; "memory" clobber pins
  // these writes below it). [64 q][20 p] fp32 per wave.
  float* etile = (float*)smem + wid * 1280;  // 4 x 5120B = 20KB < 32KB

#pragma unroll
  for (int mi = 0; mi < 4; ++mi) {
    const int prow = p0 + wrow * 64 + mi * 16 + rg4;
#pragma unroll
    for (int ni = 0; ni < 4; ++ni) {
      floatx4 vv = acc[mi][ni] * rnp[mi] * rnq[ni];
      const int qc = q0 + wcol * 64 + ni * 16 + cl;
      if (tm == tn) {
        const int d = qc - prow;  // diag when prow + r == qc
        if (d >= 0 && d < 4) vv[d] = 1.0f;
      }
      // normal tile: 4 scalar stores -> 4 x 64B segments per instruction
      ob[(size_t)(prow + 0) * P_ + qc] = vv[0];
      ob[(size_t)(prow + 1) * P_ + qc] = vv[1];
      ob[(size_t)(prow + 2) * P_ + qc] = vv[2];
      ob[(size_t)(prow + 3) * P_ + qc] = vv[3];
      if (tm != tn)  // stash transposed: lane's 4 consecutive p at row q
        *reinterpret_cast<floatx4*>(&etile[(ni * 16 + cl) * 20 + rg4]) = vv;
    }
    if (tm != tn) {
      // coalesced mirror store for this 16-col (p) slab: rows q, 64B segments
      const int pcb = p0 + wrow * 64 + mi * 16;
#pragma unroll
      for (int i = 0; i < 4; ++i) {
        const int qq = i * 16 + (lane >> 2);
        const floatx4 mv = *reinterpret_cast<const floatx4*>(&etile[qq * 20 + (lane & 3) * 4]);
        *reinterpret_cast<floatx4*>(
            &ob[(size_t)(q0 + wcol * 64 + qq) * P_ + pcb + (lane & 3) * 4]) = mv;
      }
    }
  }
}

extern "C" void kernel_launch(void* const* d_in, const int* in_sizes, int n_in,
                              void* d_out, int out_size, void* d_ws, size_t ws_size,
                              hipStream_t stream) {
  const float* x = (const float*)d_in[0];
  float* out = (float*)d_out;

  short* Xt = (short*)d_ws;                                                     // 16 MB
  float* nrm2p = (float*)((char*)d_ws + (size_t)B_ * P_ * C_ * sizeof(short));  // 2x128 KB

  k_transpose<<<dim3(P_ / 128, B_, 2), 256, 0, stream>>>(x, Xt, nrm2p);
  k_gemm<<<dim3(NT * B_), 256, 0, stream>>>(Xt, nrm2p, out);
}